// Round 10
// baseline (41.007 us; speedup 1.0000x reference)
//
#include <hip/hip_runtime.h>
#include <cstdint>

#define T_ 16
#define Z_ 33
#define K_ 32
#define FV_ 784
#define B_ 128
#define M_ 8
#define NSTEP_ 4
#define SEP_ 50
#define NOISE_N (64u * 32768u)

// ws layout (floats)
#define GN_OFF    0u
#define LPSEG_OFF 2097152u              // 128*528 = 67584
#define PLW_OFF   (LPSEG_OFF + 67584u)  // 16*1089 = 17424
#define LPM_OFF   (PLW_OFF + 17424u)    // 1024
#define CNT_OFF   (LPM_OFF + 1024u)     // 1 uint
#define WS_NEED_BYTES ((size_t)(CNT_OFF + 16u) * 4)

__device__ __forceinline__ uint32_t rotl32(uint32_t v, int r) {
  return (v << r) | (v >> (32 - r));
}

// Threefry-2x32, 20 rounds — matches JAX's threefry2x32 exactly.
__device__ __forceinline__ void tf2x32(uint32_t k0, uint32_t k1,
                                       uint32_t& x0, uint32_t& x1) {
  uint32_t k2 = k0 ^ k1 ^ 0x1BD11BDAu;
  x0 += k0; x1 += k1;
#define RND_(r) { x0 += x1; x1 = rotl32(x1, r); x1 ^= x0; }
  RND_(13) RND_(15) RND_(26) RND_(6)
  x0 += k1; x1 += k2 + 1u;
  RND_(17) RND_(29) RND_(16) RND_(24)
  x0 += k2; x1 += k0 + 2u;
  RND_(13) RND_(15) RND_(26) RND_(6)
  x0 += k0; x1 += k1 + 3u;
  RND_(17) RND_(29) RND_(16) RND_(24)
  x0 += k1; x1 += k2 + 4u;
  RND_(13) RND_(15) RND_(26) RND_(6)
  x0 += k2; x1 += k0 + 5u;
#undef RND_
}

// gumbel from raw bits, JAX bit path, fast-math logs (proven 0-ulp output since R5)
__device__ __forceinline__ float gumbel_fast(uint32_t bits) {
  const float TINY = 1.17549435e-38f;
  float u = __uint_as_float((bits >> 9) | 0x3F800000u) - 1.0f;
  u = fmaxf(TINY, u * (1.0f - TINY) + TINY);
  return -__logf(-__logf(u));
}

// precise-log gumbel (fallback path)
__device__ __forceinline__ float gumbel_bits(uint32_t bits) {
  const float TINY = 1.17549435e-38f;
  float u = __uint_as_float((bits >> 9) | 0x3F800000u) - 1.0f;
  u = fmaxf(TINY, u * (1.0f - TINY) + TINY);
  return -logf(-logf(u));
}

template <int CTRL>
__device__ __forceinline__ float dpp_f(float x) {
  int xi = __float_as_int(x);
  int r = __builtin_amdgcn_update_dpp(xi, xi, CTRL, 0xF, 0xF, false);
  return __int_as_float(r);
}

// ---------------- fast path: 2 dispatches ----------------

// prep2lean (R9-proven, all fast-math): [0,1024) gumbel noise; [1024,1552) lp_seg;
// [1552,1555) log_softmax; [1555] zero completion counter.
__global__ __launch_bounds__(256) void ZBML3_prep2lean(
    const float* __restrict__ img, const float* __restrict__ whz,
    const float* __restrict__ bias_p, const float* __restrict__ bso_p,
    const float* __restrict__ prior, float* __restrict__ ws) {
  const int bid = blockIdx.x, tid = threadIdx.x;
  float* gn = ws + GN_OFF;
  float* lpseg = ws + LPSEG_OFF;
  float* plw = ws + PLW_OFF;
  if (bid < 1024) {
    const uint32_t g = (uint32_t)(bid * 256 + tid);
    const uint32_t i = g >> 12;              // step index 0..63 (uniform per block)
    const uint32_t jb = g & 4095u;
    uint32_t k0 = 0u, k1 = i;
    tf2x32(0u, 42u, k0, k1);                 // fold_in(key(42), i)
    float* out = gn + (size_t)i * 32768u;
#pragma unroll
    for (uint32_t jj = 0; jj < 4; ++jj) {
      uint32_t j = jb + jj * 4096u;
      uint32_t x0 = j, x1 = j + 16384u;
      tf2x32(k0, k1, x0, x1);
      out[j] = gumbel_fast(x0);
      out[j + 16384u] = gumbel_fast(x1);
    }
  } else if (bid < 1024 + 528) {
    const int e = bid - 1024;               // e = t*33 + z
    if (tid < B_) {
      const int b = tid;
      const float bias0 = bias_p[0];
      const float scale = __expf(bso_p[0]);
      const float con = -__logf(scale) - 0.9189385332046727f;
      const int t = e / 33;
      const int v0 = t * SEP_;                    // always even
      const int v1 = (v0 + SEP_ < FV_) ? v0 + SEP_ : FV_;  // always even (784)
      const int nv2 = (v1 - v0) >> 1;
      const float2* wp2 = (const float2*)(whz + (size_t)e * FV_ + v0);
      const float2* xp2 = (const float2*)(img + (size_t)b * FV_ + v0);
      float acc = 0.0f;
      for (int j = 0; j < nv2; ++j) {
        float2 xv = xp2[j], wv = wp2[j];
        float d0 = (xv.x - (wv.x + bias0)) / scale;
        acc += -0.5f * d0 * d0;
        float d1 = (xv.y - (wv.y + bias0)) / scale;
        acc += -0.5f * d1 * d1;
      }
      lpseg[b * 528 + e] = acc + (float)(v1 - v0) * con;
    }
  } else if (bid < 1555) {
    const int r = (bid - 1552) * 256 + tid;
    if (r < 528) {
      const float* pr = prior + r * 33;
      float mx = pr[0];
      for (int z = 1; z < 33; ++z) mx = fmaxf(mx, pr[z]);
      float sse = 0.0f;
      for (int z = 0; z < 33; ++z) sse += __expf(pr[z] - mx);
      float lg = __logf(sse);
      for (int z = 0; z < 33; ++z) plw[r * 33 + z] = pr[z] - mx - lg;
    }
  } else {
    if (tid == 0) ((unsigned int*)(ws + CNT_OFF))[0] = 0u;
  }
}

// gibbs6 (R8-proven): gibbs5 chain + last-block-fused final (atomic counter).
// 128 blocks x 256 threads. Block = image b; 8 chains (m = tid>>5), 32 lanes each.
__global__ __launch_bounds__(256) void ZBML3_gibbs6(
    const float* __restrict__ gn, const float* __restrict__ lpseg,
    const float* __restrict__ plw_g, float* __restrict__ lpm,
    unsigned int* __restrict__ cnt, float* __restrict__ out) {
  __shared__ float pl[T_ * 1089];     // 69696 B
  __shared__ float sseg[528];         // lp_seg row for this b
  __shared__ unsigned int lastflag;

  const int b = blockIdx.x;
  const int tid = threadIdx.x;
  const int k = tid & 31;
  const int m = tid >> 5;
  const int half = m & 1;
  const uint32_t idx = (uint32_t)(b * 256 + tid);  // flat (b,m,k)

  // stage plw (4356 float4) and lp_seg row (132 float4) into LDS
  {
    const float4* src = (const float4*)plw_g;
    float4* dst = (float4*)pl;
#pragma unroll
    for (int it = 0; it < 17; ++it) {
      int j = it * 256 + tid;
      if (j < 4356) dst[j] = src[j];
    }
    const float4* ss = (const float4*)(lpseg + b * 528);
    float4* dd = (float4*)sseg;
    if (tid < 132) dd[tid] = ss[tid];
  }

  // register prefetch of step-0..15 gumbels (global, independent of LDS)
  float g0[T_];
#pragma unroll
  for (int t = 0; t < T_; ++t) g0[t] = gn[(size_t)t * 32768u + idx];

  __syncthreads();

  float sl[T_];
#pragma unroll
  for (int t = 0; t < T_; ++t) sl[t] = sseg[t * 33 + k];

  int s[T_];
#pragma unroll
  for (int t = 0; t < T_; ++t) s[t] = 0;

  // c[t] = gumbel + lp_seg[t][k] + pl[t+1][k][s[t+1]]  (initial s = 0)
  float c[T_];
#pragma unroll
  for (int t = 0; t < T_; ++t) {
    float pn = (t < T_ - 1) ? pl[(t + 1) * 1089 + k * 33] : 0.0f;
    c[t] = g0[t] + sl[t] + pn;
  }

#pragma unroll
  for (int w = 0; w < NSTEP_; ++w) {
    if (w < NSTEP_ - 1) {
#pragma unroll
      for (int t = 0; t < T_; ++t)
        g0[t] = gn[(size_t)((w + 1) * 16 + t) * 32768u + idx];
    }
#pragma unroll
    for (int t = 0; t < T_; ++t) {
      const int p = (t == 0) ? 0 : s[t - 1];
      float v = c[t] + pl[t * 1089 + p * 33 + k];
      // 32-lane max per chain, all-VALU:
      float rm = v;
      rm = fmaxf(rm, dpp_f<0x121>(rm));   // row_ror:1
      rm = fmaxf(rm, dpp_f<0x122>(rm));   // row_ror:2
      rm = fmaxf(rm, dpp_f<0x124>(rm));   // row_ror:4
      rm = fmaxf(rm, dpp_f<0x128>(rm));   // row_ror:8  -> 16-row max
      float bc = dpp_f<0x142>(rm);        // row_bcast15
      float m2 = fmaxf(rm, bc);           // lane31 = half0 max, lane63 = half1 max
      int mAi = __builtin_amdgcn_readlane(__float_as_int(m2), 31);
      int mBi = __builtin_amdgcn_readlane(__float_as_int(m2), 63);
      float vmax = __int_as_float(half == 0 ? mAi : mBi);
      unsigned long long ball = __ballot(v == vmax);
      int kA = __ffs((unsigned int)ball) - 1;
      int kB = __ffs((unsigned int)(ball >> 32)) - 1;
      s[t] = (half == 0) ? kA : kB;       // first-index tie-break = JAX argmax
    }
    if (w < NSTEP_ - 1) {
#pragma unroll
      for (int t = 0; t < T_; ++t) {
        float pn = (t < T_ - 1) ? pl[(t + 1) * 1089 + k * 33 + s[t + 1]] : 0.0f;
        c[t] = g0[t] + sl[t] + pn;
      }
    }
  }

  // final lp_m = full joint log-prob of final assignment (LDS only)
  float lpf = 0.0f;
  int prev = 0;
#pragma unroll
  for (int t = 0; t < T_; ++t) {
    lpf += sseg[t * 33 + s[t]] + pl[t * 1089 + prev * 33 + s[t]];
    prev = s[t];
  }
  if (k == 0) lpm[b * 8 + m] = lpf;

  // fused final: last-arriving block computes LSE over m and mean over b (R4/R8-proven)
  __threadfence();
  if (tid == 0) lastflag = atomicAdd(cnt, 1u);
  __syncthreads();
  if (lastflag == B_ - 1) {
    __threadfence();
    float lse = 0.0f;
    if (tid < B_) {
      const float* lp = lpm + tid * 8;
      float mx = lp[0];
#pragma unroll
      for (int mm = 1; mm < M_; ++mm) mx = fmaxf(mx, lp[mm]);
      float sse = 0.0f;
#pragma unroll
      for (int mm = 0; mm < M_; ++mm) sse += __expf(lp[mm] - mx);
      lse = mx + __logf(sse);
    }
    __syncthreads();                  // sseg reads done; reuse as scratch
    if (tid < B_) sseg[tid] = lse;
    __syncthreads();
    if (tid == 0) {
      float sum = 0.0f;
      for (int i = 0; i < B_; ++i) sum += sseg[i];
      out[0] = -(sum * (1.0f / 128.0f));
    }
  }
}

// ---------------- fallback path (round-0 monolithic kernel) ----------------

__global__ __launch_bounds__(256) void ZBML3_gibbs_kernel(
    const float* __restrict__ img, const float* __restrict__ whz,
    const float* __restrict__ bias_p, const float* __restrict__ bso_p,
    const float* __restrict__ prior, float* __restrict__ lse_out) {
  __shared__ float pl[T_ * Z_ * Z_];
  __shared__ float slseg[T_ * Z_];
  __shared__ float xrow[FV_];
  __shared__ uint32_t key0s[NSTEP_ * T_], key1s[NSTEP_ * T_];
  __shared__ float lpm[M_];

  const int b = blockIdx.x;
  const int tid = threadIdx.x;
  const float bias0 = bias_p[0];
  const float scale = expf(bso_p[0]);
  const float con = -logf(scale) - 0.9189385332046727f;

  for (int v = tid; v < FV_; v += 256) xrow[v] = img[b * FV_ + v];
  __syncthreads();

  for (int e = tid; e < T_ * Z_; e += 256) {
    int t = e / Z_;
    int v0 = t * SEP_;
    int v1 = v0 + SEP_ < FV_ ? v0 + SEP_ : FV_;
    float acc = 0.0f;
    const float* wp = whz + (size_t)e * FV_;
    for (int v = v0; v < v1; ++v) {
      float d = (xrow[v] - (wp[v] + bias0)) / scale;
      acc += -0.5f * d * d;
    }
    slseg[e] = acc + (float)(v1 - v0) * con;
  }
  for (int r = tid; r < T_ * Z_; r += 256) {
    const float* pr = prior + r * Z_;
    float mx = pr[0];
    for (int z = 1; z < Z_; ++z) mx = fmaxf(mx, pr[z]);
    float sse = 0.0f;
    for (int z = 0; z < Z_; ++z) sse += expf(pr[z] - mx);
    float lg = logf(sse);
    for (int z = 0; z < Z_; ++z) pl[r * Z_ + z] = pr[z] - mx - lg;
  }
  if (tid < NSTEP_ * T_) {
    uint32_t x0 = 0u, x1 = (uint32_t)tid;
    tf2x32(0u, 42u, x0, x1);
    key0s[tid] = x0; key1s[tid] = x1;
  }
  __syncthreads();

  const int m = tid >> 5;
  const int k = tid & 31;
  const uint32_t idx = (uint32_t)(b * 256 + tid);
  const uint32_t jctr = idx & 16383u;
  const bool sel0 = idx < 16384u;

  int s[T_];
#pragma unroll
  for (int t = 0; t < T_; ++t) s[t] = 0;

  for (int sweep = 0; sweep < NSTEP_; ++sweep) {
#pragma unroll
    for (int t = 0; t < T_; ++t) {
      const int i = sweep * T_ + t;
      const uint32_t kk0 = key0s[i], kk1 = key1s[i];
      const int p = (t == 0) ? 0 : s[t - 1];
      float lp = slseg[t * Z_ + k] + pl[t * Z_ * Z_ + p * Z_ + k];
      if (t < T_ - 1) lp += pl[(t + 1) * Z_ * Z_ + k * Z_ + s[t + 1]];
      uint32_t x0 = jctr, x1 = jctr + 16384u;
      tf2x32(kk0, kk1, x0, x1);
      float g = gumbel_bits(sel0 ? x0 : x1);
      float val = lp + g;
      int ki = k;
      for (int d = 16; d > 0; d >>= 1) {
        float ov = __shfl_xor(val, d);
        int oi = __shfl_xor(ki, d);
        if (ov > val || (ov == val && oi < ki)) { val = ov; ki = oi; }
      }
      s[t] = ki;
    }
  }

  float lpf = 0.0f;
  int prev = 0;
#pragma unroll
  for (int t = 0; t < T_; ++t) {
    lpf += slseg[t * Z_ + s[t]] + pl[t * Z_ * Z_ + prev * Z_ + s[t]];
    prev = s[t];
  }
  if (k == 0) lpm[m] = lpf;
  __syncthreads();
  if (tid == 0) {
    float mx = lpm[0];
    for (int mm = 1; mm < M_; ++mm) mx = fmaxf(mx, lpm[mm]);
    float sse = 0.0f;
    for (int mm = 0; mm < M_; ++mm) sse += expf(lpm[mm] - mx);
    lse_out[b] = mx + logf(sse);
  }
}

__global__ __launch_bounds__(128) void ZBML3_reduce_kernel(
    const float* __restrict__ lse, float* __restrict__ out) {
  __shared__ float sm[B_];
  const int tid = threadIdx.x;
  sm[tid] = lse[tid];
  __syncthreads();
  if (tid == 0) {
    float s = 0.0f;
    for (int i = 0; i < B_; ++i) s += sm[i];
    out[0] = -(s / (float)B_);
  }
}

extern "C" void kernel_launch(void* const* d_in, const int* in_sizes, int n_in,
                              void* d_out, int out_size, void* d_ws, size_t ws_size,
                              hipStream_t stream) {
  const float* img   = (const float*)d_in[0];
  const float* whz   = (const float*)d_in[1];
  const float* bias  = (const float*)d_in[2];
  const float* bso   = (const float*)d_in[3];
  const float* prior = (const float*)d_in[4];

  if (ws_size >= WS_NEED_BYTES) {
    float* ws = (float*)d_ws;
    ZBML3_prep2lean<<<1556, 256, 0, stream>>>(img, whz, bias, bso, prior, ws);
    ZBML3_gibbs6<<<B_, 256, 0, stream>>>(ws + GN_OFF, ws + LPSEG_OFF,
                                         ws + PLW_OFF, ws + LPM_OFF,
                                         (unsigned int*)(ws + CNT_OFF),
                                         (float*)d_out);
  } else {
    float* lse = (float*)d_ws;
    ZBML3_gibbs_kernel<<<B_, 256, 0, stream>>>(img, whz, bias, bso, prior, lse);
    ZBML3_reduce_kernel<<<1, B_, 0, stream>>>(lse, (float*)d_out);
  }
}

// Round 11
// 32.343 us; speedup vs baseline: 1.2679x; 1.2679x over previous
//
#include <hip/hip_runtime.h>
#include <cstdint>

#define T_ 16
#define Z_ 33
#define K_ 32
#define FV_ 784
#define B_ 128
#define M_ 8
#define NSTEP_ 4
#define SEP_ 50
#define NOISE_N (64u * 32768u)

// ws layout (floats)
#define GN_OFF    0u
#define LPSEG_OFF 2097152u              // 128*528 = 67584
#define PLW_OFF   (LPSEG_OFF + 67584u)  // 16*1089 = 17424
#define LPM_OFF   (PLW_OFF + 17424u)    // 1024 (fallback-path lse also fits)
#define WS_NEED_BYTES ((size_t)(LPM_OFF + 1024u + 16u) * 4)

__device__ __forceinline__ uint32_t rotl32(uint32_t v, int r) {
  return (v << r) | (v >> (32 - r));
}

// Threefry-2x32, 20 rounds — matches JAX's threefry2x32 exactly.
__device__ __forceinline__ void tf2x32(uint32_t k0, uint32_t k1,
                                       uint32_t& x0, uint32_t& x1) {
  uint32_t k2 = k0 ^ k1 ^ 0x1BD11BDAu;
  x0 += k0; x1 += k1;
#define RND_(r) { x0 += x1; x1 = rotl32(x1, r); x1 ^= x0; }
  RND_(13) RND_(15) RND_(26) RND_(6)
  x0 += k1; x1 += k2 + 1u;
  RND_(17) RND_(29) RND_(16) RND_(24)
  x0 += k2; x1 += k0 + 2u;
  RND_(13) RND_(15) RND_(26) RND_(6)
  x0 += k0; x1 += k1 + 3u;
  RND_(17) RND_(29) RND_(16) RND_(24)
  x0 += k1; x1 += k2 + 4u;
  RND_(13) RND_(15) RND_(26) RND_(6)
  x0 += k2; x1 += k0 + 5u;
#undef RND_
}

// gumbel from raw bits, JAX bit path, fast-math logs (proven 0-ulp output since R5)
__device__ __forceinline__ float gumbel_fast(uint32_t bits) {
  const float TINY = 1.17549435e-38f;
  float u = __uint_as_float((bits >> 9) | 0x3F800000u) - 1.0f;
  u = fmaxf(TINY, u * (1.0f - TINY) + TINY);
  return -__logf(-__logf(u));
}

// precise-log gumbel (fallback path)
__device__ __forceinline__ float gumbel_bits(uint32_t bits) {
  const float TINY = 1.17549435e-38f;
  float u = __uint_as_float((bits >> 9) | 0x3F800000u) - 1.0f;
  u = fmaxf(TINY, u * (1.0f - TINY) + TINY);
  return -logf(-logf(u));
}

template <int CTRL>
__device__ __forceinline__ float dpp_f(float x) {
  int xi = __float_as_int(x);
  int r = __builtin_amdgcn_update_dpp(xi, xi, CTRL, 0xF, 0xF, false);
  return __int_as_float(r);
}

// ---------------- fast path: 2 dispatches, no fences ----------------

// prep2lean (R9-proven, all fast-math): [0,1024) gumbel noise; [1024,1552) lp_seg;
// [1552,1555) log_softmax; [1555] zero out[0] (stream-ordered before gibbs).
__global__ __launch_bounds__(256) void ZBML3_prep2lean(
    const float* __restrict__ img, const float* __restrict__ whz,
    const float* __restrict__ bias_p, const float* __restrict__ bso_p,
    const float* __restrict__ prior, float* __restrict__ ws,
    float* __restrict__ out) {
  const int bid = blockIdx.x, tid = threadIdx.x;
  float* gn = ws + GN_OFF;
  float* lpseg = ws + LPSEG_OFF;
  float* plw = ws + PLW_OFF;
  if (bid < 1024) {
    const uint32_t g = (uint32_t)(bid * 256 + tid);
    const uint32_t i = g >> 12;              // step index 0..63 (uniform per block)
    const uint32_t jb = g & 4095u;
    uint32_t k0 = 0u, k1 = i;
    tf2x32(0u, 42u, k0, k1);                 // fold_in(key(42), i)
    float* out_g = gn + (size_t)i * 32768u;
#pragma unroll
    for (uint32_t jj = 0; jj < 4; ++jj) {
      uint32_t j = jb + jj * 4096u;
      uint32_t x0 = j, x1 = j + 16384u;
      tf2x32(k0, k1, x0, x1);
      out_g[j] = gumbel_fast(x0);
      out_g[j + 16384u] = gumbel_fast(x1);
    }
  } else if (bid < 1024 + 528) {
    const int e = bid - 1024;               // e = t*33 + z
    if (tid < B_) {
      const int b = tid;
      const float bias0 = bias_p[0];
      const float scale = __expf(bso_p[0]);
      const float con = -__logf(scale) - 0.9189385332046727f;
      const int t = e / 33;
      const int v0 = t * SEP_;                    // always even
      const int v1 = (v0 + SEP_ < FV_) ? v0 + SEP_ : FV_;  // always even (784)
      const int nv2 = (v1 - v0) >> 1;
      const float2* wp2 = (const float2*)(whz + (size_t)e * FV_ + v0);
      const float2* xp2 = (const float2*)(img + (size_t)b * FV_ + v0);
      float acc = 0.0f;
      for (int j = 0; j < nv2; ++j) {
        float2 xv = xp2[j], wv = wp2[j];
        float d0 = (xv.x - (wv.x + bias0)) / scale;
        acc += -0.5f * d0 * d0;
        float d1 = (xv.y - (wv.y + bias0)) / scale;
        acc += -0.5f * d1 * d1;
      }
      lpseg[b * 528 + e] = acc + (float)(v1 - v0) * con;
    }
  } else if (bid < 1555) {
    const int r = (bid - 1552) * 256 + tid;
    if (r < 528) {
      const float* pr = prior + r * 33;
      float mx = pr[0];
      for (int z = 1; z < 33; ++z) mx = fmaxf(mx, pr[z]);
      float sse = 0.0f;
      for (int z = 0; z < 33; ++z) sse += __expf(pr[z] - mx);
      float lg = __logf(sse);
      for (int z = 0; z < 33; ++z) plw[r * 33 + z] = pr[z] - mx - lg;
    }
  } else {
    if (tid == 0) out[0] = 0.0f;   // replay-deterministic accumulator reset
  }
}

// gibbs7 = R9's proven gibbs5 chain + block-local LSE + one atomicAdd per block.
// 128 blocks x 256 threads. Block = image b; 8 chains (m = tid>>5), 32 lanes each.
__global__ __launch_bounds__(256) void ZBML3_gibbs7(
    const float* __restrict__ gn, const float* __restrict__ lpseg,
    const float* __restrict__ plw_g, float* __restrict__ out) {
  __shared__ float pl[T_ * 1089];     // 69696 B
  __shared__ float sseg[528];         // lp_seg row for this b

  const int b = blockIdx.x;
  const int tid = threadIdx.x;
  const int k = tid & 31;
  const int m = tid >> 5;
  const int half = m & 1;
  const uint32_t idx = (uint32_t)(b * 256 + tid);  // flat (b,m,k)

  // stage plw (4356 float4) and lp_seg row (132 float4) into LDS
  {
    const float4* src = (const float4*)plw_g;
    float4* dst = (float4*)pl;
#pragma unroll
    for (int it = 0; it < 17; ++it) {
      int j = it * 256 + tid;
      if (j < 4356) dst[j] = src[j];
    }
    const float4* ss = (const float4*)(lpseg + b * 528);
    float4* dd = (float4*)sseg;
    if (tid < 132) dd[tid] = ss[tid];
  }

  // register prefetch of step-0..15 gumbels (global, independent of LDS)
  float g0[T_];
#pragma unroll
  for (int t = 0; t < T_; ++t) g0[t] = gn[(size_t)t * 32768u + idx];

  __syncthreads();

  float sl[T_];
#pragma unroll
  for (int t = 0; t < T_; ++t) sl[t] = sseg[t * 33 + k];

  int s[T_];
#pragma unroll
  for (int t = 0; t < T_; ++t) s[t] = 0;

  // c[t] = gumbel + lp_seg[t][k] + pl[t+1][k][s[t+1]]  (initial s = 0)
  float c[T_];
#pragma unroll
  for (int t = 0; t < T_; ++t) {
    float pn = (t < T_ - 1) ? pl[(t + 1) * 1089 + k * 33] : 0.0f;
    c[t] = g0[t] + sl[t] + pn;
  }

#pragma unroll
  for (int w = 0; w < NSTEP_; ++w) {
    if (w < NSTEP_ - 1) {
#pragma unroll
      for (int t = 0; t < T_; ++t)
        g0[t] = gn[(size_t)((w + 1) * 16 + t) * 32768u + idx];
    }
#pragma unroll
    for (int t = 0; t < T_; ++t) {
      const int p = (t == 0) ? 0 : s[t - 1];
      float v = c[t] + pl[t * 1089 + p * 33 + k];
      // 32-lane max per chain, all-VALU:
      float rm = v;
      rm = fmaxf(rm, dpp_f<0x121>(rm));   // row_ror:1
      rm = fmaxf(rm, dpp_f<0x122>(rm));   // row_ror:2
      rm = fmaxf(rm, dpp_f<0x124>(rm));   // row_ror:4
      rm = fmaxf(rm, dpp_f<0x128>(rm));   // row_ror:8  -> 16-row max
      float bc = dpp_f<0x142>(rm);        // row_bcast15
      float m2 = fmaxf(rm, bc);           // lane31 = half0 max, lane63 = half1 max
      int mAi = __builtin_amdgcn_readlane(__float_as_int(m2), 31);
      int mBi = __builtin_amdgcn_readlane(__float_as_int(m2), 63);
      float vmax = __int_as_float(half == 0 ? mAi : mBi);
      unsigned long long ball = __ballot(v == vmax);
      int kA = __ffs((unsigned int)ball) - 1;
      int kB = __ffs((unsigned int)(ball >> 32)) - 1;
      s[t] = (half == 0) ? kA : kB;       // first-index tie-break = JAX argmax
    }
    if (w < NSTEP_ - 1) {
#pragma unroll
      for (int t = 0; t < T_; ++t) {
        float pn = (t < T_ - 1) ? pl[(t + 1) * 1089 + k * 33 + s[t + 1]] : 0.0f;
        c[t] = g0[t] + sl[t] + pn;
      }
    }
  }

  // final lp_m = full joint log-prob of final assignment (LDS only)
  float lpf = 0.0f;
  int prev = 0;
#pragma unroll
  for (int t = 0; t < T_; ++t) {
    lpf += sseg[t * 33 + s[t]] + pl[t * 1089 + prev * 33 + s[t]];
    prev = s[t];
  }

  // block-local LSE over the 8 chains, then one atomicAdd (no fence, no spin)
  __syncthreads();                    // all sseg/pl reads above are complete
  if (k == 0) sseg[m] = lpf;          // reuse sseg[0..7]
  __syncthreads();
  if (tid == 0) {
    float mx = sseg[0];
#pragma unroll
    for (int mm = 1; mm < M_; ++mm) mx = fmaxf(mx, sseg[mm]);
    float sse = 0.0f;
#pragma unroll
    for (int mm = 0; mm < M_; ++mm) sse += __expf(sseg[mm] - mx);
    float lse = mx + __logf(sse);
    atomicAdd(out, -lse * (1.0f / 128.0f));
  }
}

// ---------------- fallback path (round-0 monolithic kernel) ----------------

__global__ __launch_bounds__(256) void ZBML3_gibbs_kernel(
    const float* __restrict__ img, const float* __restrict__ whz,
    const float* __restrict__ bias_p, const float* __restrict__ bso_p,
    const float* __restrict__ prior, float* __restrict__ lse_out) {
  __shared__ float pl[T_ * Z_ * Z_];
  __shared__ float slseg[T_ * Z_];
  __shared__ float xrow[FV_];
  __shared__ uint32_t key0s[NSTEP_ * T_], key1s[NSTEP_ * T_];
  __shared__ float lpm[M_];

  const int b = blockIdx.x;
  const int tid = threadIdx.x;
  const float bias0 = bias_p[0];
  const float scale = expf(bso_p[0]);
  const float con = -logf(scale) - 0.9189385332046727f;

  for (int v = tid; v < FV_; v += 256) xrow[v] = img[b * FV_ + v];
  __syncthreads();

  for (int e = tid; e < T_ * Z_; e += 256) {
    int t = e / Z_;
    int v0 = t * SEP_;
    int v1 = v0 + SEP_ < FV_ ? v0 + SEP_ : FV_;
    float acc = 0.0f;
    const float* wp = whz + (size_t)e * FV_;
    for (int v = v0; v < v1; ++v) {
      float d = (xrow[v] - (wp[v] + bias0)) / scale;
      acc += -0.5f * d * d;
    }
    slseg[e] = acc + (float)(v1 - v0) * con;
  }
  for (int r = tid; r < T_ * Z_; r += 256) {
    const float* pr = prior + r * Z_;
    float mx = pr[0];
    for (int z = 1; z < Z_; ++z) mx = fmaxf(mx, pr[z]);
    float sse = 0.0f;
    for (int z = 0; z < Z_; ++z) sse += expf(pr[z] - mx);
    float lg = logf(sse);
    for (int z = 0; z < Z_; ++z) pl[r * Z_ + z] = pr[z] - mx - lg;
  }
  if (tid < NSTEP_ * T_) {
    uint32_t x0 = 0u, x1 = (uint32_t)tid;
    tf2x32(0u, 42u, x0, x1);
    key0s[tid] = x0; key1s[tid] = x1;
  }
  __syncthreads();

  const int m = tid >> 5;
  const int k = tid & 31;
  const uint32_t idx = (uint32_t)(b * 256 + tid);
  const uint32_t jctr = idx & 16383u;
  const bool sel0 = idx < 16384u;

  int s[T_];
#pragma unroll
  for (int t = 0; t < T_; ++t) s[t] = 0;

  for (int sweep = 0; sweep < NSTEP_; ++sweep) {
#pragma unroll
    for (int t = 0; t < T_; ++t) {
      const int i = sweep * T_ + t;
      const uint32_t kk0 = key0s[i], kk1 = key1s[i];
      const int p = (t == 0) ? 0 : s[t - 1];
      float lp = slseg[t * Z_ + k] + pl[t * Z_ * Z_ + p * Z_ + k];
      if (t < T_ - 1) lp += pl[(t + 1) * Z_ * Z_ + k * Z_ + s[t + 1]];
      uint32_t x0 = jctr, x1 = jctr + 16384u;
      tf2x32(kk0, kk1, x0, x1);
      float g = gumbel_bits(sel0 ? x0 : x1);
      float val = lp + g;
      int ki = k;
      for (int d = 16; d > 0; d >>= 1) {
        float ov = __shfl_xor(val, d);
        int oi = __shfl_xor(ki, d);
        if (ov > val || (ov == val && oi < ki)) { val = ov; ki = oi; }
      }
      s[t] = ki;
    }
  }

  float lpf = 0.0f;
  int prev = 0;
#pragma unroll
  for (int t = 0; t < T_; ++t) {
    lpf += slseg[t * Z_ + s[t]] + pl[t * Z_ * Z_ + prev * Z_ + s[t]];
    prev = s[t];
  }
  if (k == 0) lpm[m] = lpf;
  __syncthreads();
  if (tid == 0) {
    float mx = lpm[0];
    for (int mm = 1; mm < M_; ++mm) mx = fmaxf(mx, lpm[mm]);
    float sse = 0.0f;
    for (int mm = 0; mm < M_; ++mm) sse += expf(lpm[mm] - mx);
    lse_out[b] = mx + logf(sse);
  }
}

__global__ __launch_bounds__(128) void ZBML3_reduce_kernel(
    const float* __restrict__ lse, float* __restrict__ out) {
  __shared__ float sm[B_];
  const int tid = threadIdx.x;
  sm[tid] = lse[tid];
  __syncthreads();
  if (tid == 0) {
    float s = 0.0f;
    for (int i = 0; i < B_; ++i) s += sm[i];
    out[0] = -(s / (float)B_);
  }
}

extern "C" void kernel_launch(void* const* d_in, const int* in_sizes, int n_in,
                              void* d_out, int out_size, void* d_ws, size_t ws_size,
                              hipStream_t stream) {
  const float* img   = (const float*)d_in[0];
  const float* whz   = (const float*)d_in[1];
  const float* bias  = (const float*)d_in[2];
  const float* bso   = (const float*)d_in[3];
  const float* prior = (const float*)d_in[4];

  if (ws_size >= WS_NEED_BYTES) {
    float* ws = (float*)d_ws;
    ZBML3_prep2lean<<<1556, 256, 0, stream>>>(img, whz, bias, bso, prior, ws,
                                              (float*)d_out);
    ZBML3_gibbs7<<<B_, 256, 0, stream>>>(ws + GN_OFF, ws + LPSEG_OFF,
                                         ws + PLW_OFF, (float*)d_out);
  } else {
    float* lse = (float*)d_ws;
    ZBML3_gibbs_kernel<<<B_, 256, 0, stream>>>(img, whz, bias, bso, prior, lse);
    ZBML3_reduce_kernel<<<1, B_, 0, stream>>>(lse, (float*)d_out);
  }
}